// Round 1
// baseline (1419.661 us; speedup 1.0000x reference)
//
#include <hip/hip_runtime.h>

#define HD 128
#define NN 50000
#define NE 600000
#define EPB 16
#define NPB 16

// SiLU
__device__ __forceinline__ float silu(float x) {
    return x / (1.0f + __expf(-x));
}

__global__ __launch_bounds__(128) void egnn_edge_kernel(
    const float* __restrict__ h, const float* __restrict__ pos,
    const int* __restrict__ ei,
    const float* __restrict__ mw1, const float* __restrict__ mb1,
    const float* __restrict__ mw2, const float* __restrict__ mb2,
    const float* __restrict__ cw1, const float* __restrict__ cb1,
    const float* __restrict__ cw2, const float* __restrict__ cb2,
    float* __restrict__ agg_msg, float* __restrict__ agg_trans)
{
    __shared__ __align__(16) float xs[EPB][260];   // [h_row 128 | h_col 128 | radial | pad]
    __shared__ __align__(16) float ts[EPB][HD];    // silu(layer1)
    __shared__ float cd[EPB][3];
    __shared__ float c1s[EPB][4];

    const int j  = threadIdx.x;            // output channel 0..127
    const int e0 = blockIdx.x * EPB;

    // ---- gather ----
    for (int b = 0; b < EPB; ++b) {
        const int e = e0 + b;
        const int r = ei[e];               // row (scalar, uniform)
        const int c = ei[NE + e];          // col
        xs[b][j]      = h[(size_t)r * HD + j];
        xs[b][HD + j] = h[(size_t)c * HD + j];
        if (j < 3) cd[b][j] = pos[r * 3 + j] - pos[c * 3 + j];
    }
    __syncthreads();
    if (j < EPB) {
        const float d0 = cd[j][0], d1 = cd[j][1], d2 = cd[j][2];
        xs[j][256] = d0*d0 + d1*d1 + d2*d2 + 1e-8f;
    }
    __syncthreads();

    // ---- layer 1: [EPB,257] @ [257,128] ----
    float acc[EPB];
    {
        const float bj = mb1[j];
        #pragma unroll
        for (int b = 0; b < EPB; ++b) acc[b] = bj;
    }
    for (int k4 = 0; k4 < 64; ++k4) {
        const float w0 = mw1[(k4*4 + 0)*HD + j];
        const float w1 = mw1[(k4*4 + 1)*HD + j];
        const float w2 = mw1[(k4*4 + 2)*HD + j];
        const float w3 = mw1[(k4*4 + 3)*HD + j];
        #pragma unroll
        for (int b = 0; b < EPB; ++b) {
            const float4 x = *reinterpret_cast<const float4*>(&xs[b][k4*4]);
            acc[b] = fmaf(x.x, w0, acc[b]);
            acc[b] = fmaf(x.y, w1, acc[b]);
            acc[b] = fmaf(x.z, w2, acc[b]);
            acc[b] = fmaf(x.w, w3, acc[b]);
        }
    }
    {   // k = 256 (radial row)
        const float w = mw1[256*HD + j];
        #pragma unroll
        for (int b = 0; b < EPB; ++b) acc[b] = fmaf(xs[b][256], w, acc[b]);
    }
    #pragma unroll
    for (int b = 0; b < EPB; ++b) ts[b][j] = silu(acc[b]);
    __syncthreads();

    // ---- layer 2: [EPB,128] @ [128,128] -> msg ----
    float msg[EPB];
    {
        const float bj = mb2[j];
        #pragma unroll
        for (int b = 0; b < EPB; ++b) msg[b] = bj;
    }
    for (int k4 = 0; k4 < 32; ++k4) {
        const float w0 = mw2[(k4*4 + 0)*HD + j];
        const float w1 = mw2[(k4*4 + 1)*HD + j];
        const float w2 = mw2[(k4*4 + 2)*HD + j];
        const float w3 = mw2[(k4*4 + 3)*HD + j];
        #pragma unroll
        for (int b = 0; b < EPB; ++b) {
            const float4 t = *reinterpret_cast<const float4*>(&ts[b][k4*4]);
            msg[b] = fmaf(t.x, w0, msg[b]);
            msg[b] = fmaf(t.y, w1, msg[b]);
            msg[b] = fmaf(t.z, w2, msg[b]);
            msg[b] = fmaf(t.w, w3, msg[b]);
        }
    }

    // stash msg into xs's first 128 columns for the coord MLP
    #pragma unroll
    for (int b = 0; b < EPB; ++b) xs[b][j] = msg[b];
    __syncthreads();

    // ---- coord MLP: silu(msg @ cw1 + cb1) @ cw2 + cb2 ----
    if (j < EPB * 4) {
        const int b = j >> 2, q = j & 3;
        float s = cb1[q];
        for (int k4 = 0; k4 < 32; ++k4) {
            const float4 m = *reinterpret_cast<const float4*>(&xs[b][k4*4]);
            s = fmaf(m.x, cw1[(k4*4 + 0)*4 + q], s);
            s = fmaf(m.y, cw1[(k4*4 + 1)*4 + q], s);
            s = fmaf(m.z, cw1[(k4*4 + 2)*4 + q], s);
            s = fmaf(m.w, cw1[(k4*4 + 3)*4 + q], s);
        }
        c1s[b][q] = silu(s);
    }
    __syncthreads();

    // ---- scatter trans (3 atomics/edge) ----
    if (j < EPB * 3) {
        const int b = j / 3, a = j % 3;
        const float cw = cb2[0] + c1s[b][0]*cw2[0] + c1s[b][1]*cw2[1]
                       + c1s[b][2]*cw2[2] + c1s[b][3]*cw2[3];
        const int r = ei[e0 + b];
        atomicAdd(&agg_trans[r * 3 + a], cd[b][a] * cw);
    }

    // ---- scatter msg (128 atomics/edge, coalesced across j) ----
    #pragma unroll
    for (int b = 0; b < EPB; ++b) {
        const int r = ei[e0 + b];
        atomicAdd(&agg_msg[(size_t)r * HD + j], msg[b]);
    }
}

__global__ __launch_bounds__(128) void egnn_node_kernel(
    const float* __restrict__ h, const float* __restrict__ pos,
    const float* __restrict__ nw1, const float* __restrict__ nb1,
    const float* __restrict__ nw2, const float* __restrict__ nb2,
    float* __restrict__ out_h,    // holds agg_msg on entry; h_new on exit
    float* __restrict__ out_pos)  // holds agg_trans on entry; pos_new on exit
{
    __shared__ __align__(16) float xs[NPB][256];   // [h | agg_msg]
    __shared__ __align__(16) float ts[NPB][HD];

    const int j  = threadIdx.x;
    const int n0 = blockIdx.x * NPB;

    for (int b = 0; b < NPB; ++b) {
        const int n = n0 + b;
        xs[b][j]      = h[(size_t)n * HD + j];
        xs[b][HD + j] = out_h[(size_t)n * HD + j];
    }
    __syncthreads();

    float acc[NPB];
    {
        const float bj = nb1[j];
        #pragma unroll
        for (int b = 0; b < NPB; ++b) acc[b] = bj;
    }
    for (int k4 = 0; k4 < 64; ++k4) {
        const float w0 = nw1[(k4*4 + 0)*HD + j];
        const float w1 = nw1[(k4*4 + 1)*HD + j];
        const float w2 = nw1[(k4*4 + 2)*HD + j];
        const float w3 = nw1[(k4*4 + 3)*HD + j];
        #pragma unroll
        for (int b = 0; b < NPB; ++b) {
            const float4 x = *reinterpret_cast<const float4*>(&xs[b][k4*4]);
            acc[b] = fmaf(x.x, w0, acc[b]);
            acc[b] = fmaf(x.y, w1, acc[b]);
            acc[b] = fmaf(x.z, w2, acc[b]);
            acc[b] = fmaf(x.w, w3, acc[b]);
        }
    }
    #pragma unroll
    for (int b = 0; b < NPB; ++b) ts[b][j] = silu(acc[b]);
    __syncthreads();

    float acc2[NPB];
    {
        const float bj = nb2[j];
        #pragma unroll
        for (int b = 0; b < NPB; ++b) acc2[b] = bj;
    }
    for (int k4 = 0; k4 < 32; ++k4) {
        const float w0 = nw2[(k4*4 + 0)*HD + j];
        const float w1 = nw2[(k4*4 + 1)*HD + j];
        const float w2 = nw2[(k4*4 + 2)*HD + j];
        const float w3 = nw2[(k4*4 + 3)*HD + j];
        #pragma unroll
        for (int b = 0; b < NPB; ++b) {
            const float4 t = *reinterpret_cast<const float4*>(&ts[b][k4*4]);
            acc2[b] = fmaf(t.x, w0, acc2[b]);
            acc2[b] = fmaf(t.y, w1, acc2[b]);
            acc2[b] = fmaf(t.z, w2, acc2[b]);
            acc2[b] = fmaf(t.w, w3, acc2[b]);
        }
    }

    // h_new = h + out  (xs[b][j] still holds h)
    #pragma unroll
    for (int b = 0; b < NPB; ++b)
        out_h[(size_t)(n0 + b) * HD + j] = xs[b][j] + acc2[b];

    // pos_new = pos + agg_trans (in place)
    if (j < NPB * 3) {
        const int b = j / 3, a = j % 3;
        const size_t idx = (size_t)(n0 + b) * 3 + a;
        out_pos[idx] = pos[idx] + out_pos[idx];
    }
}

extern "C" void kernel_launch(void* const* d_in, const int* in_sizes, int n_in,
                              void* d_out, int out_size, void* d_ws, size_t ws_size,
                              hipStream_t stream) {
    const float* h   = (const float*)d_in[0];
    const float* pos = (const float*)d_in[1];
    const int*   ei  = (const int*)d_in[2];
    const float* mw1 = (const float*)d_in[3];
    const float* mb1 = (const float*)d_in[4];
    const float* mw2 = (const float*)d_in[5];
    const float* mb2 = (const float*)d_in[6];
    const float* cw1 = (const float*)d_in[7];
    const float* cb1 = (const float*)d_in[8];
    const float* cw2 = (const float*)d_in[9];
    const float* cb2 = (const float*)d_in[10];
    const float* nw1 = (const float*)d_in[11];
    const float* nb1 = (const float*)d_in[12];
    const float* nw2 = (const float*)d_in[13];
    const float* nb2 = (const float*)d_in[14];

    float* out     = (float*)d_out;
    float* out_h   = out;                          // 50000*128 floats
    float* out_pos = out + (size_t)NN * HD;        // 50000*3 floats

    // zero the output (it doubles as the aggregation buffer) — every call,
    // since the harness does not re-poison between replays
    hipMemsetAsync(d_out, 0, (size_t)out_size * sizeof(float), stream);

    egnn_edge_kernel<<<NE / EPB, 128, 0, stream>>>(
        h, pos, ei, mw1, mb1, mw2, mb2, cw1, cb1, cw2, cb2, out_h, out_pos);

    egnn_node_kernel<<<NN / NPB, 128, 0, stream>>>(
        h, pos, nw1, nb1, nw2, nb2, out_h, out_pos);
}

// Round 2
// 458.373 us; speedup vs baseline: 3.0972x; 3.0972x over previous
//
#include <hip/hip_runtime.h>

#define HD 128
#define NN 50000
#define NE 600000
#define EPB 32            // edges per block (edge kernel)
#define NPB 16            // nodes per block (node kernel)
#define XST 296           // X LDS row stride in bf16 (K padded 288 + slack; 2-way bank alias = free)
#define TST 136           // T/M LDS row stride in bf16
#define K1P 288           // padded K for layer1 (257 -> 288), zero-padded weights
#define NB_E (NE / EPB)   // 18750

typedef __attribute__((ext_vector_type(8))) short short8v;   // 8 bf16 = 16 B
typedef __attribute__((ext_vector_type(4))) short short4v;   // 4 bf16 = 8 B
typedef __attribute__((ext_vector_type(4))) float f32x4;

#define MFMA_BF16(a, b, c) __builtin_amdgcn_mfma_f32_16x16x32_bf16(a, b, c, 0, 0, 0)

__device__ __forceinline__ float silu(float x) {
    return x / (1.0f + __expf(-x));
}
__device__ __forceinline__ unsigned short f2bf(float x) {   // RNE f32 -> bf16
    unsigned u = __float_as_uint(x);
    unsigned r = (u + 0x7FFFu + ((u >> 16) & 1u)) >> 16;
    return (unsigned short)r;
}
__device__ __forceinline__ float bf2f(unsigned short u) {
    return __uint_as_float((unsigned)u << 16);
}

// ---- prep: transpose+convert weights to bf16 in ws ----
// w1t[c][k] (c<128, k<288): mw1[k*128+c] for k<257 else 0
// w2t[c][k] (c<128, k<128): mw2[k*128+c]
__global__ __launch_bounds__(256) void prep_weights(
    const float* __restrict__ mw1, const float* __restrict__ mw2,
    unsigned short* __restrict__ w1t, unsigned short* __restrict__ w2t)
{
    int idx = blockIdx.x * 256 + threadIdx.x;
    if (idx < 128 * K1P) {
        int c = idx / K1P, k = idx % K1P;
        w1t[idx] = (k < 257) ? f2bf(mw1[(size_t)k * HD + c]) : (unsigned short)0;
    } else if (idx < 128 * K1P + 128 * 128) {
        int i = idx - 128 * K1P;
        int c = i / 128, k = i % 128;
        w2t[i] = f2bf(mw2[(size_t)k * HD + c]);
    }
}

// ---- prep: h -> bf16 ----
__global__ __launch_bounds__(256) void prep_h(
    const float* __restrict__ h, unsigned short* __restrict__ hb)
{
    size_t idx = (size_t)(blockIdx.x * 256 + threadIdx.x) * 4;
    float4 f = *reinterpret_cast<const float4*>(h + idx);
    short4v v;
    v[0] = (short)f2bf(f.x); v[1] = (short)f2bf(f.y);
    v[2] = (short)f2bf(f.z); v[3] = (short)f2bf(f.w);
    *reinterpret_cast<short4v*>(hb + idx) = v;
}

// ---- edge kernel: bf16 MFMA ----
template <int USE_HB>
__global__ __launch_bounds__(256) void egnn_edge_mfma(
    const float* __restrict__ h, const unsigned short* __restrict__ hb,
    const float* __restrict__ pos, const int* __restrict__ ei,
    const unsigned short* __restrict__ w1t, const float* __restrict__ mb1,
    const unsigned short* __restrict__ w2t, const float* __restrict__ mb2,
    const float* __restrict__ cw1, const float* __restrict__ cb1,
    const float* __restrict__ cw2, const float* __restrict__ cb2,
    float* __restrict__ agg_msg, float* __restrict__ agg_trans)
{
    __shared__ __align__(16) unsigned short X[EPB * XST];  // gathered [h_r|h_c|radial|0pad]; reused for msg
    __shared__ __align__(16) unsigned short T[EPB * TST];  // silu(layer1) bf16
    __shared__ int rows[EPB], cols[EPB];
    __shared__ float cd[EPB][3];
    __shared__ float c1s[EPB][4];

    const int tid  = threadIdx.x;
    const int lane = tid & 63;
    const int w    = tid >> 6;          // wave 0..3
    const int lr   = lane & 15;         // row/col within 16-tile
    const int lk   = (lane >> 4) * 8;   // k-chunk base within 32
    const int c0   = w * 32;            // this wave's output-channel base
    const int e0   = blockIdx.x * EPB;

    // edge indices + zero X pad columns (256..295; col 256 re-written with radial)
    if (tid < EPB) rows[tid] = ei[e0 + tid];
    else if (tid < 2 * EPB) cols[tid - EPB] = ei[(size_t)NE + e0 + (tid - EPB)];
    for (int idx = tid; idx < EPB * 40; idx += 256) {
        int e = idx / 40, c = 256 + idx % 40;
        X[e * XST + c] = 0;
    }
    __syncthreads();   // S1

    // coord diff
    if (tid < EPB * 3) {
        int e = tid / 3, a = tid % 3;
        cd[e][a] = pos[rows[e] * 3 + a] - pos[cols[e] * 3 + a];
    }
    // gather h (64 row-slots: 32x h[row] -> cols 0..127, 32x h[col] -> cols 128..255)
    // 16 threads x 8 bf16 per row-slot, 4 passes
    for (int pass = 0; pass < 4; ++pass) {
        const int slot = pass * 16 + (tid >> 4);
        const int p    = tid & 15;
        const int e    = slot & 31;
        const int off  = (slot < 32) ? 0 : 128;
        const int src  = (slot < 32) ? rows[e] : cols[e];
        short8v v;
        if (USE_HB) {
            v = *reinterpret_cast<const short8v*>(hb + (size_t)src * HD + p * 8);
        } else {
            const float* hp = h + (size_t)src * HD + p * 8;
            float4 f0 = *reinterpret_cast<const float4*>(hp);
            float4 f1 = *reinterpret_cast<const float4*>(hp + 4);
            v[0] = (short)f2bf(f0.x); v[1] = (short)f2bf(f0.y);
            v[2] = (short)f2bf(f0.z); v[3] = (short)f2bf(f0.w);
            v[4] = (short)f2bf(f1.x); v[5] = (short)f2bf(f1.y);
            v[6] = (short)f2bf(f1.z); v[7] = (short)f2bf(f1.w);
        }
        *reinterpret_cast<short8v*>(&X[e * XST + off + p * 8]) = v;
    }
    __syncthreads();   // S2

    if (tid < EPB) {
        float d0 = cd[tid][0], d1 = cd[tid][1], d2 = cd[tid][2];
        X[tid * XST + 256] = f2bf(d0 * d0 + d1 * d1 + d2 * d2 + 1e-8f);
    }
    __syncthreads();   // S3: X complete

    // ---- layer 1: X[32,288] @ W1T^T -> T[32,128] ----
    f32x4 acc1[2][2] = {};
    {
        const unsigned short* xa0 = &X[lr * XST + lk];
        const unsigned short* xa1 = xa0 + 16 * XST;
        const unsigned short* wb0 = w1t + (size_t)(c0 + lr) * K1P + lk;
        const unsigned short* wb1 = wb0 + 16 * K1P;
        #pragma unroll
        for (int ks = 0; ks < 9; ++ks) {
            const int k0 = ks * 32;
            short8v a0 = *reinterpret_cast<const short8v*>(xa0 + k0);
            short8v a1 = *reinterpret_cast<const short8v*>(xa1 + k0);
            short8v b0 = *reinterpret_cast<const short8v*>(wb0 + k0);
            short8v b1 = *reinterpret_cast<const short8v*>(wb1 + k0);
            acc1[0][0] = MFMA_BF16(a0, b0, acc1[0][0]);
            acc1[0][1] = MFMA_BF16(a0, b1, acc1[0][1]);
            acc1[1][0] = MFMA_BF16(a1, b0, acc1[1][0]);
            acc1[1][1] = MFMA_BF16(a1, b1, acc1[1][1]);
        }
    }
    {
        const float b1a = mb1[c0 + lr];
        const float b1b = mb1[c0 + 16 + lr];
        #pragma unroll
        for (int mt = 0; mt < 2; ++mt)
            #pragma unroll
            for (int nt = 0; nt < 2; ++nt) {
                const int n = c0 + nt * 16 + lr;
                const float bb = nt ? b1b : b1a;
                #pragma unroll
                for (int r = 0; r < 4; ++r) {
                    const int m = mt * 16 + (lane >> 4) * 4 + r;
                    T[m * TST + n] = f2bf(silu(acc1[mt][nt][r] + bb));
                }
            }
    }
    __syncthreads();   // S4: T complete (X reads all done)

    // ---- layer 2: T[32,128] @ W2T^T -> msg[32,128] ----
    f32x4 acc2[2][2] = {};
    {
        const unsigned short* ta0 = &T[lr * TST + lk];
        const unsigned short* ta1 = ta0 + 16 * TST;
        const unsigned short* wb0 = w2t + (size_t)(c0 + lr) * 128 + lk;
        const unsigned short* wb1 = wb0 + 16 * 128;
        #pragma unroll
        for (int ks = 0; ks < 4; ++ks) {
            const int k0 = ks * 32;
            short8v a0 = *reinterpret_cast<const short8v*>(ta0 + k0);
            short8v a1 = *reinterpret_cast<const short8v*>(ta1 + k0);
            short8v b0 = *reinterpret_cast<const short8v*>(wb0 + k0);
            short8v b1 = *reinterpret_cast<const short8v*>(wb1 + k0);
            acc2[0][0] = MFMA_BF16(a0, b0, acc2[0][0]);
            acc2[0][1] = MFMA_BF16(a0, b1, acc2[0][1]);
            acc2[1][0] = MFMA_BF16(a1, b0, acc2[1][0]);
            acc2[1][1] = MFMA_BF16(a1, b1, acc2[1][1]);
        }
    }
    // msg: stage to LDS (reuse X region) for coord MLP + atomic scatter to agg_msg
    unsigned short* M = X;
    {
        const float b2a = mb2[c0 + lr];
        const float b2b = mb2[c0 + 16 + lr];
        #pragma unroll
        for (int mt = 0; mt < 2; ++mt)
            #pragma unroll
            for (int nt = 0; nt < 2; ++nt) {
                const int n = c0 + nt * 16 + lr;
                const float bb = nt ? b2b : b2a;
                #pragma unroll
                for (int r = 0; r < 4; ++r) {
                    const int m = mt * 16 + (lane >> 4) * 4 + r;
                    const float v = acc2[mt][nt][r] + bb;
                    M[m * TST + n] = f2bf(v);
                    atomicAdd(&agg_msg[(size_t)rows[m] * HD + n], v);
                }
            }
    }
    __syncthreads();   // S5: M complete

    // ---- coord MLP: silu(msg @ cw1 + cb1) @ cw2 + cb2 ----
    if (tid < EPB * 4) {
        const int e = tid >> 2, q = tid & 3;
        float s = cb1[q];
        #pragma unroll
        for (int k8 = 0; k8 < 16; ++k8) {
            short8v mm = *reinterpret_cast<const short8v*>(&M[e * TST + k8 * 8]);
            #pragma unroll
            for (int j = 0; j < 8; ++j)
                s = fmaf(bf2f((unsigned short)mm[j]), cw1[(k8 * 8 + j) * 4 + q], s);
        }
        c1s[e][q] = silu(s);
    }
    __syncthreads();   // S6

    if (tid < EPB * 3) {
        const int e = tid / 3, a = tid % 3;
        const float cwt = cb2[0] + c1s[e][0] * cw2[0] + c1s[e][1] * cw2[1]
                        + c1s[e][2] * cw2[2] + c1s[e][3] * cw2[3];
        atomicAdd(&agg_trans[rows[e] * 3 + a], cd[e][a] * cwt);
    }
}

// ---- node kernel (f32, unchanged from round 1) ----
__global__ __launch_bounds__(128) void egnn_node_kernel(
    const float* __restrict__ h, const float* __restrict__ pos,
    const float* __restrict__ nw1, const float* __restrict__ nb1,
    const float* __restrict__ nw2, const float* __restrict__ nb2,
    float* __restrict__ out_h, float* __restrict__ out_pos)
{
    __shared__ __align__(16) float xs[NPB][256];
    __shared__ __align__(16) float ts[NPB][HD];

    const int j  = threadIdx.x;
    const int n0 = blockIdx.x * NPB;

    for (int b = 0; b < NPB; ++b) {
        const int n = n0 + b;
        xs[b][j]      = h[(size_t)n * HD + j];
        xs[b][HD + j] = out_h[(size_t)n * HD + j];
    }
    __syncthreads();

    float acc[NPB];
    {
        const float bj = nb1[j];
        #pragma unroll
        for (int b = 0; b < NPB; ++b) acc[b] = bj;
    }
    for (int k4 = 0; k4 < 64; ++k4) {
        const float w0 = nw1[(k4 * 4 + 0) * HD + j];
        const float w1 = nw1[(k4 * 4 + 1) * HD + j];
        const float w2 = nw1[(k4 * 4 + 2) * HD + j];
        const float w3 = nw1[(k4 * 4 + 3) * HD + j];
        #pragma unroll
        for (int b = 0; b < NPB; ++b) {
            const float4 x = *reinterpret_cast<const float4*>(&xs[b][k4 * 4]);
            acc[b] = fmaf(x.x, w0, acc[b]);
            acc[b] = fmaf(x.y, w1, acc[b]);
            acc[b] = fmaf(x.z, w2, acc[b]);
            acc[b] = fmaf(x.w, w3, acc[b]);
        }
    }
    #pragma unroll
    for (int b = 0; b < NPB; ++b) ts[b][j] = silu(acc[b]);
    __syncthreads();

    float acc2[NPB];
    {
        const float bj = nb2[j];
        #pragma unroll
        for (int b = 0; b < NPB; ++b) acc2[b] = bj;
    }
    for (int k4 = 0; k4 < 32; ++k4) {
        const float w0 = nw2[(k4 * 4 + 0) * HD + j];
        const float w1 = nw2[(k4 * 4 + 1) * HD + j];
        const float w2 = nw2[(k4 * 4 + 2) * HD + j];
        const float w3 = nw2[(k4 * 4 + 3) * HD + j];
        #pragma unroll
        for (int b = 0; b < NPB; ++b) {
            const float4 t = *reinterpret_cast<const float4*>(&ts[b][k4 * 4]);
            acc2[b] = fmaf(t.x, w0, acc2[b]);
            acc2[b] = fmaf(t.y, w1, acc2[b]);
            acc2[b] = fmaf(t.z, w2, acc2[b]);
            acc2[b] = fmaf(t.w, w3, acc2[b]);
        }
    }

    #pragma unroll
    for (int b = 0; b < NPB; ++b)
        out_h[(size_t)(n0 + b) * HD + j] = xs[b][j] + acc2[b];

    if (j < NPB * 3) {
        const int b = j / 3, a = j % 3;
        const size_t idx = (size_t)(n0 + b) * 3 + a;
        out_pos[idx] = pos[idx] + out_pos[idx];
    }
}

extern "C" void kernel_launch(void* const* d_in, const int* in_sizes, int n_in,
                              void* d_out, int out_size, void* d_ws, size_t ws_size,
                              hipStream_t stream) {
    const float* h   = (const float*)d_in[0];
    const float* pos = (const float*)d_in[1];
    const int*   ei  = (const int*)d_in[2];
    const float* mw1 = (const float*)d_in[3];
    const float* mb1 = (const float*)d_in[4];
    const float* mw2 = (const float*)d_in[5];
    const float* mb2 = (const float*)d_in[6];
    const float* cw1 = (const float*)d_in[7];
    const float* cb1 = (const float*)d_in[8];
    const float* cw2 = (const float*)d_in[9];
    const float* cb2 = (const float*)d_in[10];
    const float* nw1 = (const float*)d_in[11];
    const float* nb1 = (const float*)d_in[12];
    const float* nw2 = (const float*)d_in[13];
    const float* nb2 = (const float*)d_in[14];

    float* out     = (float*)d_out;
    float* out_h   = out;                       // agg_msg -> h_new
    float* out_pos = out + (size_t)NN * HD;     // agg_trans -> pos_new

    // ws layout: [w1t 128*288 bf16][w2t 128*128 bf16][hb 50000*128 bf16]
    unsigned short* w1t = (unsigned short*)d_ws;
    unsigned short* w2t = w1t + 128 * K1P;
    unsigned short* hb  = w1t + 128 * K1P + 128 * 128;
    const size_t need_hb = (size_t)(128 * K1P + 128 * 128) * 2 + (size_t)NN * HD * 2;
    const int use_hb = (ws_size >= need_hb) ? 1 : 0;

    prep_weights<<<(128 * K1P + 128 * 128 + 255) / 256, 256, 0, stream>>>(mw1, mw2, w1t, w2t);
    if (use_hb)
        prep_h<<<(NN * HD / 4 + 255) / 256, 256, 0, stream>>>(h, hb);

    hipMemsetAsync(d_out, 0, (size_t)out_size * sizeof(float), stream);

    if (use_hb)
        egnn_edge_mfma<1><<<NB_E, 256, 0, stream>>>(
            h, hb, pos, ei, w1t, mb1, w2t, mb2, cw1, cb1, cw2, cb2, out_h, out_pos);
    else
        egnn_edge_mfma<0><<<NB_E, 256, 0, stream>>>(
            h, hb, pos, ei, w1t, mb1, w2t, mb2, cw1, cb1, cw2, cb2, out_h, out_pos);

    egnn_node_kernel<<<NN / NPB, 128, 0, stream>>>(
        h, pos, nw1, nb1, nw2, nb2, out_h, out_pos);
}

// Round 3
// 360.533 us; speedup vs baseline: 3.9377x; 1.2714x over previous
//
#include <hip/hip_runtime.h>

#define HD 128
#define NN 50000
#define NE 600000
#define EPB 32            // edges per block (edge kernel)
#define NPB 32            // nodes per block (node kernel)
#define XST 296           // edge X LDS row stride (bf16): 148 dwords -> 2-way bank alias = free
#define TST 136           // T/M LDS row stride (bf16)
#define K1P 288           // padded K for edge layer1
#define NXST 264          // node X LDS row stride (bf16): 132 dwords -> 2-way = free
#define NB_E (NE / EPB)   // 18750
#define NB_N ((NN + NPB - 1) / NPB)  // 1563 (tail block handles 16)

typedef __attribute__((ext_vector_type(8))) short short8v;   // 8 bf16 = 16 B
typedef __attribute__((ext_vector_type(4))) short short4v;   // 4 bf16 = 8 B
typedef __attribute__((ext_vector_type(4))) float f32x4;

#define MFMA_BF16(a, b, c) __builtin_amdgcn_mfma_f32_16x16x32_bf16(a, b, c, 0, 0, 0)

__device__ __forceinline__ float silu(float x) {
    return x / (1.0f + __expf(-x));
}
__device__ __forceinline__ unsigned short f2bf(float x) {   // RNE f32 -> bf16
    unsigned u = __float_as_uint(x);
    unsigned r = (u + 0x7FFFu + ((u >> 16) & 1u)) >> 16;
    return (unsigned short)r;
}
__device__ __forceinline__ float bf2f(unsigned short u) {
    return __uint_as_float((unsigned)u << 16);
}

// ---- prep: transpose+convert all four GEMM weights to bf16 in ws ----
// layout (bf16 entries): w1t[128][288] | w2t[128][128] | n1t[128][256] | n2t[128][128]
#define W1T_N (128 * K1P)          // 36864
#define W2T_N (128 * 128)          // 16384
#define N1T_N (128 * 256)          // 32768
#define N2T_N (128 * 128)          // 16384
#define WTOT  (W1T_N + W2T_N + N1T_N + N2T_N)  // 102400

__global__ __launch_bounds__(256) void prep_weights(
    const float* __restrict__ mw1, const float* __restrict__ mw2,
    const float* __restrict__ nw1, const float* __restrict__ nw2,
    unsigned short* __restrict__ wt)
{
    int idx = blockIdx.x * 256 + threadIdx.x;
    if (idx < W1T_N) {
        int c = idx / K1P, k = idx % K1P;
        wt[idx] = (k < 257) ? f2bf(mw1[(size_t)k * HD + c]) : (unsigned short)0;
    } else if (idx < W1T_N + W2T_N) {
        int i = idx - W1T_N;
        int c = i / 128, k = i % 128;
        wt[idx] = f2bf(mw2[(size_t)k * HD + c]);
    } else if (idx < W1T_N + W2T_N + N1T_N) {
        int i = idx - (W1T_N + W2T_N);
        int c = i / 256, k = i % 256;
        wt[idx] = f2bf(nw1[(size_t)k * HD + c]);
    } else if (idx < WTOT) {
        int i = idx - (W1T_N + W2T_N + N1T_N);
        int c = i / 128, k = i % 128;
        wt[idx] = f2bf(nw2[(size_t)k * HD + c]);
    }
}

// ---- prep: h -> bf16 ----
__global__ __launch_bounds__(256) void prep_h(
    const float* __restrict__ h, unsigned short* __restrict__ hb)
{
    size_t idx = (size_t)(blockIdx.x * 256 + threadIdx.x) * 4;
    float4 f = *reinterpret_cast<const float4*>(h + idx);
    short4v v;
    v[0] = (short)f2bf(f.x); v[1] = (short)f2bf(f.y);
    v[2] = (short)f2bf(f.z); v[3] = (short)f2bf(f.w);
    *reinterpret_cast<short4v*>(hb + idx) = v;
}

// ============ edge kernel: bf16 MFMA, 4 barriers, LDS-aliased ============
template <int USE_HB>
__global__ __launch_bounds__(256, 8) void egnn_edge_mfma(
    const float* __restrict__ h, const unsigned short* __restrict__ hb,
    const float* __restrict__ pos, const int* __restrict__ ei,
    const unsigned short* __restrict__ w1t, const float* __restrict__ mb1,
    const unsigned short* __restrict__ w2t, const float* __restrict__ mb2,
    const float* __restrict__ cw1, const float* __restrict__ cb1,
    const float* __restrict__ cw2, const float* __restrict__ cb2,
    float* __restrict__ agg_msg, float* __restrict__ agg_trans)
{
    // X[32][296] bf16. Live ranges (separated by barriers):
    //   phase A: gathered [h_r|h_c|radial|0pad], entries [0, 9472)
    //   phase B: T = silu(layer1) bf16, entries [0, 4352), stride TST
    //   phase C: M = msg bf16,          entries [4608, 8960), stride TST
    __shared__ __align__(16) unsigned short X[EPB * XST];
    __shared__ int rows[EPB];
    __shared__ float cd[EPB][3];

    const int tid  = threadIdx.x;
    const int lane = tid & 63;
    const int w    = tid >> 6;
    const int lr   = lane & 15;
    const int lk   = (lane >> 4) * 8;
    const int c0   = w * 32;
    const int e0   = blockIdx.x * EPB;

    // ---- phase 0: indices, coord-diff, radial, pad, gather (no pre-barrier) ----
    if (tid < EPB) {
        const int r = ei[e0 + tid];
        const int c = ei[(size_t)NE + e0 + tid];
        rows[tid] = r;
        const float d0 = pos[r * 3 + 0] - pos[c * 3 + 0];
        const float d1 = pos[r * 3 + 1] - pos[c * 3 + 1];
        const float d2 = pos[r * 3 + 2] - pos[c * 3 + 2];
        cd[tid][0] = d0; cd[tid][1] = d1; cd[tid][2] = d2;
        X[tid * XST + 256] = f2bf(d0 * d0 + d1 * d1 + d2 * d2 + 1e-8f);
    }
    for (int idx = tid; idx < EPB * 31; idx += 256) {   // zero pad cols 257..287
        const int e = idx / 31, c = 257 + idx % 31;
        X[e * XST + c] = 0;
    }
    #pragma unroll
    for (int p = 0; p < 4; ++p) {       // 64 row-slots x 256B, 16 thr x 16B each
        const int slot  = p * 16 + (tid >> 4);
        const int pc    = tid & 15;
        const int e     = slot & 31;
        const int iscol = slot >> 5;
        const int src   = ei[(size_t)(iscol ? NE : 0) + e0 + e];
        short8v v;
        if (USE_HB) {
            v = *reinterpret_cast<const short8v*>(hb + (size_t)src * HD + pc * 8);
        } else {
            const float* hp = h + (size_t)src * HD + pc * 8;
            float4 f0 = *reinterpret_cast<const float4*>(hp);
            float4 f1 = *reinterpret_cast<const float4*>(hp + 4);
            v[0] = (short)f2bf(f0.x); v[1] = (short)f2bf(f0.y);
            v[2] = (short)f2bf(f0.z); v[3] = (short)f2bf(f0.w);
            v[4] = (short)f2bf(f1.x); v[5] = (short)f2bf(f1.y);
            v[6] = (short)f2bf(f1.z); v[7] = (short)f2bf(f1.w);
        }
        *reinterpret_cast<short8v*>(&X[e * XST + iscol * 128 + pc * 8]) = v;
    }
    __syncthreads();   // B1: X complete

    // ---- layer 1: X[32,288] @ W1T^T -> acc1 ----
    f32x4 acc1[2][2] = {};
    {
        const unsigned short* xa0 = &X[lr * XST + lk];
        const unsigned short* xa1 = xa0 + 16 * XST;
        const unsigned short* wb0 = w1t + (size_t)(c0 + lr) * K1P + lk;
        const unsigned short* wb1 = wb0 + 16 * K1P;
        #pragma unroll
        for (int ks = 0; ks < 9; ++ks) {
            const int k0 = ks * 32;
            short8v a0 = *reinterpret_cast<const short8v*>(xa0 + k0);
            short8v a1 = *reinterpret_cast<const short8v*>(xa1 + k0);
            short8v b0 = *reinterpret_cast<const short8v*>(wb0 + k0);
            short8v b1 = *reinterpret_cast<const short8v*>(wb1 + k0);
            acc1[0][0] = MFMA_BF16(a0, b0, acc1[0][0]);
            acc1[0][1] = MFMA_BF16(a0, b1, acc1[0][1]);
            acc1[1][0] = MFMA_BF16(a1, b0, acc1[1][0]);
            acc1[1][1] = MFMA_BF16(a1, b1, acc1[1][1]);
        }
    }
    __syncthreads();   // B2: all waves' X reads retired -> safe to alias

    // ---- silu -> T (aliased into X[0, 4352)) ----
    {
        unsigned short* T = X;
        const float b1a = mb1[c0 + lr];
        const float b1b = mb1[c0 + 16 + lr];
        #pragma unroll
        for (int mt = 0; mt < 2; ++mt)
            #pragma unroll
            for (int nt = 0; nt < 2; ++nt) {
                const int n = c0 + nt * 16 + lr;
                const float bb = nt ? b1b : b1a;
                #pragma unroll
                for (int r = 0; r < 4; ++r) {
                    const int m = mt * 16 + (lane >> 4) * 4 + r;
                    T[m * TST + n] = f2bf(silu(acc1[mt][nt][r] + bb));
                }
            }
    }
    __syncthreads();   // B3: T complete

    // ---- layer 2: T[32,128] @ W2T^T -> msg ----
    f32x4 acc2[2][2] = {};
    {
        const unsigned short* ta0 = &X[lr * TST + lk];
        const unsigned short* ta1 = ta0 + 16 * TST;
        const unsigned short* wb0 = w2t + (size_t)(c0 + lr) * 128 + lk;
        const unsigned short* wb1 = wb0 + 16 * 128;
        #pragma unroll
        for (int ks = 0; ks < 4; ++ks) {
            const int k0 = ks * 32;
            short8v a0 = *reinterpret_cast<const short8v*>(ta0 + k0);
            short8v a1 = *reinterpret_cast<const short8v*>(ta1 + k0);
            short8v b0 = *reinterpret_cast<const short8v*>(wb0 + k0);
            short8v b1 = *reinterpret_cast<const short8v*>(wb1 + k0);
            acc2[0][0] = MFMA_BF16(a0, b0, acc2[0][0]);
            acc2[0][1] = MFMA_BF16(a0, b1, acc2[0][1]);
            acc2[1][0] = MFMA_BF16(a1, b0, acc2[1][0]);
            acc2[1][1] = MFMA_BF16(a1, b1, acc2[1][1]);
        }
    }
    // msg: stage bf16 to M (X entries [4608, 8960), disjoint from T) + atomic scatter
    {
        unsigned short* M = X + 4608;
        const float b2a = mb2[c0 + lr];
        const float b2b = mb2[c0 + 16 + lr];
        #pragma unroll
        for (int mt = 0; mt < 2; ++mt)
            #pragma unroll
            for (int nt = 0; nt < 2; ++nt) {
                const int n = c0 + nt * 16 + lr;
                const float bb = nt ? b2b : b2a;
                #pragma unroll
                for (int r = 0; r < 4; ++r) {
                    const int m = mt * 16 + (lane >> 4) * 4 + r;
                    const float v = acc2[mt][nt][r] + bb;
                    M[m * TST + n] = f2bf(v);
                    atomicAdd(&agg_msg[(size_t)rows[m] * HD + n], v);
                }
            }
    }
    __syncthreads();   // B4: M complete

    // ---- coord MLP (barrier-free tail): lanes (e,q), shfl-reduce over q ----
    if (tid < EPB * 4) {
        const int e = tid >> 2, q = tid & 3;
        const unsigned short* M = X + 4608;
        float sa = 0.f, sb = 0.f, sc = 0.f, sd = 0.f;
        #pragma unroll
        for (int k8 = 0; k8 < 16; ++k8) {
            short8v mm = *reinterpret_cast<const short8v*>(&M[e * TST + k8 * 8]);
            const float* cwp = cw1 + (k8 * 8) * 4 + q;
            sa = fmaf(bf2f((unsigned short)mm[0]), cwp[0],  sa);
            sb = fmaf(bf2f((unsigned short)mm[1]), cwp[4],  sb);
            sc = fmaf(bf2f((unsigned short)mm[2]), cwp[8],  sc);
            sd = fmaf(bf2f((unsigned short)mm[3]), cwp[12], sd);
            sa = fmaf(bf2f((unsigned short)mm[4]), cwp[16], sa);
            sb = fmaf(bf2f((unsigned short)mm[5]), cwp[20], sb);
            sc = fmaf(bf2f((unsigned short)mm[6]), cwp[24], sc);
            sd = fmaf(bf2f((unsigned short)mm[7]), cwp[28], sd);
        }
        const float s  = cb1[q] + ((sa + sb) + (sc + sd));
        const float c1 = silu(s);
        float t = c1 * cw2[q];
        t += __shfl_xor(t, 1, 4);
        t += __shfl_xor(t, 2, 4);
        const float cwt = t + cb2[0];
        if (q < 3)
            atomicAdd(&agg_trans[rows[e] * 3 + q], cd[e][q] * cwt);
    }
}

// ============ node kernel: bf16 MFMA ============
template <int USE_HB>
__global__ __launch_bounds__(256, 6) void egnn_node_mfma(
    const float* __restrict__ h, const unsigned short* __restrict__ hb,
    const float* __restrict__ pos,
    const unsigned short* __restrict__ n1t, const float* __restrict__ nb1,
    const unsigned short* __restrict__ n2t, const float* __restrict__ nb2,
    float* __restrict__ out_h,    // holds agg_msg on entry; h_new on exit
    float* __restrict__ out_pos)  // holds agg_trans on entry; pos_new on exit
{
    __shared__ __align__(16) unsigned short Xn[NPB * NXST];  // [h bf16 | agg bf16]
    __shared__ __align__(16) unsigned short Tn[NPB * TST];

    const int tid  = threadIdx.x;
    const int lane = tid & 63;
    const int w    = tid >> 6;
    const int lr   = lane & 15;
    const int lk   = (lane >> 4) * 8;
    const int c0   = w * 32;
    const int n0   = blockIdx.x * NPB;

    // ---- load X: h (bf16) cols 0..127, agg (f32->bf16) cols 128..255 ----
    #pragma unroll
    for (int p = 0; p < 2; ++p) {
        const int s  = p * 16 + (tid >> 4);
        const int pc = tid & 15;
        int n = n0 + s; if (n >= NN) n = NN - 1;
        short8v v;
        if (USE_HB) {
            v = *reinterpret_cast<const short8v*>(hb + (size_t)n * HD + pc * 8);
        } else {
            const float* hp = h + (size_t)n * HD + pc * 8;
            float4 f0 = *reinterpret_cast<const float4*>(hp);
            float4 f1 = *reinterpret_cast<const float4*>(hp + 4);
            v[0] = (short)f2bf(f0.x); v[1] = (short)f2bf(f0.y);
            v[2] = (short)f2bf(f0.z); v[3] = (short)f2bf(f0.w);
            v[4] = (short)f2bf(f1.x); v[5] = (short)f2bf(f1.y);
            v[6] = (short)f2bf(f1.z); v[7] = (short)f2bf(f1.w);
        }
        *reinterpret_cast<short8v*>(&Xn[s * NXST + pc * 8]) = v;
    }
    #pragma unroll
    for (int p = 0; p < 4; ++p) {
        const int idx = p * 256 + tid;     // 0..1023
        const int s   = idx >> 5;          // node slot
        const int cs  = idx & 31;          // 4-float segment
        int n = n0 + s; if (n >= NN) n = NN - 1;
        float4 f = *reinterpret_cast<const float4*>(out_h + (size_t)n * HD + cs * 4);
        short4v v;
        v[0] = (short)f2bf(f.x); v[1] = (short)f2bf(f.y);
        v[2] = (short)f2bf(f.z); v[3] = (short)f2bf(f.w);
        *reinterpret_cast<short4v*>(&Xn[s * NXST + 128 + cs * 4]) = v;
    }
    __syncthreads();   // B1

    // ---- layer 1: Xn[32,256] @ N1T^T ----
    f32x4 acc1[2][2] = {};
    {
        const unsigned short* xa0 = &Xn[lr * NXST + lk];
        const unsigned short* xa1 = xa0 + 16 * NXST;
        const unsigned short* wb0 = n1t + (size_t)(c0 + lr) * 256 + lk;
        const unsigned short* wb1 = wb0 + 16 * 256;
        #pragma unroll
        for (int ks = 0; ks < 8; ++ks) {
            const int k0 = ks * 32;
            short8v a0 = *reinterpret_cast<const short8v*>(xa0 + k0);
            short8v a1 = *reinterpret_cast<const short8v*>(xa1 + k0);
            short8v b0 = *reinterpret_cast<const short8v*>(wb0 + k0);
            short8v b1 = *reinterpret_cast<const short8v*>(wb1 + k0);
            acc1[0][0] = MFMA_BF16(a0, b0, acc1[0][0]);
            acc1[0][1] = MFMA_BF16(a0, b1, acc1[0][1]);
            acc1[1][0] = MFMA_BF16(a1, b0, acc1[1][0]);
            acc1[1][1] = MFMA_BF16(a1, b1, acc1[1][1]);
        }
    }
    {
        const float b1a = nb1[c0 + lr];
        const float b1b = nb1[c0 + 16 + lr];
        #pragma unroll
        for (int mt = 0; mt < 2; ++mt)
            #pragma unroll
            for (int nt = 0; nt < 2; ++nt) {
                const int n = c0 + nt * 16 + lr;
                const float bb = nt ? b1b : b1a;
                #pragma unroll
                for (int r = 0; r < 4; ++r) {
                    const int m = mt * 16 + (lane >> 4) * 4 + r;
                    Tn[m * TST + n] = f2bf(silu(acc1[mt][nt][r] + bb));
                }
            }
    }
    __syncthreads();   // B2: Tn ready

    // ---- layer 2: Tn[32,128] @ N2T^T ----
    f32x4 acc2[2][2] = {};
    {
        const unsigned short* ta0 = &Tn[lr * TST + lk];
        const unsigned short* ta1 = ta0 + 16 * TST;
        const unsigned short* wb0 = n2t + (size_t)(c0 + lr) * 128 + lk;
        const unsigned short* wb1 = wb0 + 16 * 128;
        #pragma unroll
        for (int ks = 0; ks < 4; ++ks) {
            const int k0 = ks * 32;
            short8v a0 = *reinterpret_cast<const short8v*>(ta0 + k0);
            short8v a1 = *reinterpret_cast<const short8v*>(ta1 + k0);
            short8v b0 = *reinterpret_cast<const short8v*>(wb0 + k0);
            short8v b1 = *reinterpret_cast<const short8v*>(wb1 + k0);
            acc2[0][0] = MFMA_BF16(a0, b0, acc2[0][0]);
            acc2[0][1] = MFMA_BF16(a0, b1, acc2[0][1]);
            acc2[1][0] = MFMA_BF16(a1, b0, acc2[1][0]);
            acc2[1][1] = MFMA_BF16(a1, b1, acc2[1][1]);
        }
    }
    // ---- epilogue: h_new = h + (acc2 + nb2), in place over agg_msg ----
    {
        const float b2a = nb2[c0 + lr];
        const float b2b = nb2[c0 + 16 + lr];
        #pragma unroll
        for (int mt = 0; mt < 2; ++mt)
            #pragma unroll
            for (int nt = 0; nt < 2; ++nt) {
                const int n = c0 + nt * 16 + lr;
                const float bb = nt ? b2b : b2a;
                #pragma unroll
                for (int r = 0; r < 4; ++r) {
                    const int m = mt * 16 + (lane >> 4) * 4 + r;
                    const int node = n0 + m;
                    if (node < NN) {
                        const size_t o = (size_t)node * HD + n;
                        out_h[o] = h[o] + acc2[mt][nt][r] + bb;
                    }
                }
            }
    }
    // pos_new = pos + agg_trans (in place)
    if (tid < NPB * 3) {
        const int s = tid / 3, a = tid % 3;
        const int node = n0 + s;
        if (node < NN) {
            const size_t idx = (size_t)node * 3 + a;
            out_pos[idx] = pos[idx] + out_pos[idx];
        }
    }
}

extern "C" void kernel_launch(void* const* d_in, const int* in_sizes, int n_in,
                              void* d_out, int out_size, void* d_ws, size_t ws_size,
                              hipStream_t stream) {
    const float* h   = (const float*)d_in[0];
    const float* pos = (const float*)d_in[1];
    const int*   ei  = (const int*)d_in[2];
    const float* mw1 = (const float*)d_in[3];
    const float* mb1 = (const float*)d_in[4];
    const float* mw2 = (const float*)d_in[5];
    const float* mb2 = (const float*)d_in[6];
    const float* cw1 = (const float*)d_in[7];
    const float* cb1 = (const float*)d_in[8];
    const float* cw2 = (const float*)d_in[9];
    const float* cb2 = (const float*)d_in[10];
    const float* nw1 = (const float*)d_in[11];
    const float* nb1 = (const float*)d_in[12];
    const float* nw2 = (const float*)d_in[13];
    const float* nb2 = (const float*)d_in[14];

    float* out     = (float*)d_out;
    float* out_h   = out;                       // agg_msg -> h_new
    float* out_pos = out + (size_t)NN * HD;     // agg_trans -> pos_new

    // ws layout (bf16): [w1t|w2t|n1t|n2t : WTOT entries][hb : NN*HD entries]
    unsigned short* wt  = (unsigned short*)d_ws;
    unsigned short* w1t = wt;
    unsigned short* w2t = wt + W1T_N;
    unsigned short* n1t = wt + W1T_N + W2T_N;
    unsigned short* n2t = wt + W1T_N + W2T_N + N1T_N;
    unsigned short* hb  = wt + WTOT;
    const size_t need_hb = (size_t)WTOT * 2 + (size_t)NN * HD * 2;
    const int use_hb = (ws_size >= need_hb) ? 1 : 0;

    prep_weights<<<(WTOT + 255) / 256, 256, 0, stream>>>(mw1, mw2, nw1, nw2, wt);
    if (use_hb)
        prep_h<<<(NN * HD / 4 + 255) / 256, 256, 0, stream>>>(h, hb);

    hipMemsetAsync(d_out, 0, (size_t)out_size * sizeof(float), stream);

    if (use_hb) {
        egnn_edge_mfma<1><<<NB_E, 256, 0, stream>>>(
            h, hb, pos, ei, w1t, mb1, w2t, mb2, cw1, cb1, cw2, cb2, out_h, out_pos);
        egnn_node_mfma<1><<<NB_N, 256, 0, stream>>>(
            h, hb, pos, n1t, nb1, n2t, nb2, out_h, out_pos);
    } else {
        egnn_edge_mfma<0><<<NB_E, 256, 0, stream>>>(
            h, hb, pos, ei, w1t, mb1, w2t, mb2, cw1, cb1, cw2, cb2, out_h, out_pos);
        egnn_node_mfma<0><<<NB_N, 256, 0, stream>>>(
            h, hb, pos, n1t, nb1, n2t, nb2, out_h, out_pos);
    }
}

// Round 4
// 281.603 us; speedup vs baseline: 5.0414x; 1.2803x over previous
//
#include <hip/hip_runtime.h>

#define HD 128
#define NN 50000
#define NE 600000
#define EPB 32            // edges per block (edge kernel)
#define NPB 32            // nodes per block (node kernel)
#define XST 296           // edge X LDS row stride (bf16)
#define TST 136           // T/M LDS row stride (bf16)
#define K1P 288           // padded K for edge layer1
#define NXST 264          // node X LDS row stride (bf16)
#define NB_E (NE / EPB)   // 18750
#define NB_N ((NN + NPB - 1) / NPB)

typedef __attribute__((ext_vector_type(8))) short short8v;
typedef __attribute__((ext_vector_type(4))) short short4v;
typedef __attribute__((ext_vector_type(4))) float f32x4;

#define MFMA_BF16(a, b, c) __builtin_amdgcn_mfma_f32_16x16x32_bf16(a, b, c, 0, 0, 0)

__device__ __forceinline__ float silu(float x) {
    return x / (1.0f + __expf(-x));
}
__device__ __forceinline__ unsigned short f2bf(float x) {   // RNE f32 -> bf16
    unsigned u = __float_as_uint(x);
    unsigned r = (u + 0x7FFFu + ((u >> 16) & 1u)) >> 16;
    return (unsigned short)r;
}
__device__ __forceinline__ float bf2f(unsigned short u) {
    return __uint_as_float((unsigned)u << 16);
}
// packed bf16 atomic add (2 channels per op), fire-and-forget
__device__ __forceinline__ void atomic_pk_bf16(unsigned short* dst, unsigned pk) {
    asm volatile("global_atomic_pk_add_bf16 %0, %1, off" :: "v"(dst), "v"(pk) : "memory");
}

// ---- prep: transpose+convert all four GEMM weights to bf16 in ws ----
#define W1T_N (128 * K1P)
#define W2T_N (128 * 128)
#define N1T_N (128 * 256)
#define N2T_N (128 * 128)
#define WTOT  (W1T_N + W2T_N + N1T_N + N2T_N)  // 102400

__global__ __launch_bounds__(256) void prep_weights(
    const float* __restrict__ mw1, const float* __restrict__ mw2,
    const float* __restrict__ nw1, const float* __restrict__ nw2,
    unsigned short* __restrict__ wt)
{
    int idx = blockIdx.x * 256 + threadIdx.x;
    if (idx < W1T_N) {
        int c = idx / K1P, k = idx % K1P;
        wt[idx] = (k < 257) ? f2bf(mw1[(size_t)k * HD + c]) : (unsigned short)0;
    } else if (idx < W1T_N + W2T_N) {
        int i = idx - W1T_N;
        int c = i / 128, k = i % 128;
        wt[idx] = f2bf(mw2[(size_t)k * HD + c]);
    } else if (idx < W1T_N + W2T_N + N1T_N) {
        int i = idx - (W1T_N + W2T_N);
        int c = i / 256, k = i % 256;
        wt[idx] = f2bf(nw1[(size_t)k * HD + c]);
    } else if (idx < WTOT) {
        int i = idx - (W1T_N + W2T_N + N1T_N);
        int c = i / 128, k = i % 128;
        wt[idx] = f2bf(nw2[(size_t)k * HD + c]);
    }
}

__global__ __launch_bounds__(256) void prep_h(
    const float* __restrict__ h, unsigned short* __restrict__ hb)
{
    size_t idx = (size_t)(blockIdx.x * 256 + threadIdx.x) * 4;
    float4 f = *reinterpret_cast<const float4*>(h + idx);
    short4v v;
    v[0] = (short)f2bf(f.x); v[1] = (short)f2bf(f.y);
    v[2] = (short)f2bf(f.z); v[3] = (short)f2bf(f.w);
    *reinterpret_cast<short4v*>(hb + idx) = v;
}

// ============ edge kernel ============
// MODE 0: f32 gather from h, f32 atomics into agg_f32 (=out_h)
// MODE 2: bf16 gather from hb, packed-bf16 atomics into agg_bf
template <int MODE>
__global__ __launch_bounds__(256, 8) void egnn_edge_mfma(
    const float* __restrict__ h, const unsigned short* __restrict__ hb,
    const float* __restrict__ pos, const int* __restrict__ ei,
    const unsigned short* __restrict__ w1t, const float* __restrict__ mb1,
    const unsigned short* __restrict__ w2t, const float* __restrict__ mb2,
    const float* __restrict__ cw1, const float* __restrict__ cb1,
    const float* __restrict__ cw2, const float* __restrict__ cb2,
    float* __restrict__ agg_f32, unsigned short* __restrict__ agg_bf,
    float* __restrict__ agg_trans)
{
    // X live ranges: A) gathered [h_r|h_c|radial|pad]; B) T (silu L1) in [0,4352);
    // C) M (msg bf16) in [4608, 8960)
    __shared__ __align__(16) unsigned short X[EPB * XST];
    __shared__ int rows[EPB];
    __shared__ float cd[EPB][3];

    const int tid  = threadIdx.x;
    const int lane = tid & 63;
    const int w    = tid >> 6;
    const int lr   = lane & 15;
    const int lk   = (lane >> 4) * 8;
    const int c0   = w * 32;
    const int e0   = blockIdx.x * EPB;

    // ---- phase 0: indices, coord-diff, radial, pad, gather ----
    if (tid < EPB) {
        const int r = ei[e0 + tid];
        const int c = ei[(size_t)NE + e0 + tid];
        rows[tid] = r;
        const float d0 = pos[r * 3 + 0] - pos[c * 3 + 0];
        const float d1 = pos[r * 3 + 1] - pos[c * 3 + 1];
        const float d2 = pos[r * 3 + 2] - pos[c * 3 + 2];
        cd[tid][0] = d0; cd[tid][1] = d1; cd[tid][2] = d2;
        X[tid * XST + 256] = f2bf(d0 * d0 + d1 * d1 + d2 * d2 + 1e-8f);
    }
    for (int idx = tid; idx < EPB * 31; idx += 256) {
        const int e = idx / 31, c = 257 + idx % 31;
        X[e * XST + c] = 0;
    }
    #pragma unroll
    for (int p = 0; p < 4; ++p) {
        const int slot  = p * 16 + (tid >> 4);
        const int pc    = tid & 15;
        const int e     = slot & 31;
        const int iscol = slot >> 5;
        const int src   = ei[(size_t)(iscol ? NE : 0) + e0 + e];
        short8v v;
        if (MODE >= 1) {
            v = *reinterpret_cast<const short8v*>(hb + (size_t)src * HD + pc * 8);
        } else {
            const float* hp = h + (size_t)src * HD + pc * 8;
            float4 f0 = *reinterpret_cast<const float4*>(hp);
            float4 f1 = *reinterpret_cast<const float4*>(hp + 4);
            v[0] = (short)f2bf(f0.x); v[1] = (short)f2bf(f0.y);
            v[2] = (short)f2bf(f0.z); v[3] = (short)f2bf(f0.w);
            v[4] = (short)f2bf(f1.x); v[5] = (short)f2bf(f1.y);
            v[6] = (short)f2bf(f1.z); v[7] = (short)f2bf(f1.w);
        }
        *reinterpret_cast<short8v*>(&X[e * XST + iscol * 128 + pc * 8]) = v;
    }
    __syncthreads();   // B1: X complete

    // ---- layer 1 ----
    f32x4 acc1[2][2] = {};
    {
        const unsigned short* xa0 = &X[lr * XST + lk];
        const unsigned short* xa1 = xa0 + 16 * XST;
        const unsigned short* wb0 = w1t + (size_t)(c0 + lr) * K1P + lk;
        const unsigned short* wb1 = wb0 + 16 * K1P;
        #pragma unroll
        for (int ks = 0; ks < 9; ++ks) {
            const int k0 = ks * 32;
            short8v a0 = *reinterpret_cast<const short8v*>(xa0 + k0);
            short8v a1 = *reinterpret_cast<const short8v*>(xa1 + k0);
            short8v b0 = *reinterpret_cast<const short8v*>(wb0 + k0);
            short8v b1 = *reinterpret_cast<const short8v*>(wb1 + k0);
            acc1[0][0] = MFMA_BF16(a0, b0, acc1[0][0]);
            acc1[0][1] = MFMA_BF16(a0, b1, acc1[0][1]);
            acc1[1][0] = MFMA_BF16(a1, b0, acc1[1][0]);
            acc1[1][1] = MFMA_BF16(a1, b1, acc1[1][1]);
        }
    }
    __syncthreads();   // B2: X reads retired -> safe to alias

    {   // silu -> T (aliased into X[0,4352))
        unsigned short* T = X;
        const float b1a = mb1[c0 + lr];
        const float b1b = mb1[c0 + 16 + lr];
        #pragma unroll
        for (int mt = 0; mt < 2; ++mt)
            #pragma unroll
            for (int nt = 0; nt < 2; ++nt) {
                const int n = c0 + nt * 16 + lr;
                const float bb = nt ? b1b : b1a;
                #pragma unroll
                for (int r = 0; r < 4; ++r) {
                    const int m = mt * 16 + (lane >> 4) * 4 + r;
                    T[m * TST + n] = f2bf(silu(acc1[mt][nt][r] + bb));
                }
            }
    }
    __syncthreads();   // B3: T complete

    // ---- layer 2 ----
    f32x4 acc2[2][2] = {};
    {
        const unsigned short* ta0 = &X[lr * TST + lk];
        const unsigned short* ta1 = ta0 + 16 * TST;
        const unsigned short* wb0 = w2t + (size_t)(c0 + lr) * 128 + lk;
        const unsigned short* wb1 = wb0 + 16 * 128;
        #pragma unroll
        for (int ks = 0; ks < 4; ++ks) {
            const int k0 = ks * 32;
            short8v a0 = *reinterpret_cast<const short8v*>(ta0 + k0);
            short8v a1 = *reinterpret_cast<const short8v*>(ta1 + k0);
            short8v b0 = *reinterpret_cast<const short8v*>(wb0 + k0);
            short8v b1 = *reinterpret_cast<const short8v*>(wb1 + k0);
            acc2[0][0] = MFMA_BF16(a0, b0, acc2[0][0]);
            acc2[0][1] = MFMA_BF16(a0, b1, acc2[0][1]);
            acc2[1][0] = MFMA_BF16(a1, b0, acc2[1][0]);
            acc2[1][1] = MFMA_BF16(a1, b1, acc2[1][1]);
        }
    }
    {   // msg -> M (bf16, X entries [4608,8960)); MODE0 also does f32 atomics here
        unsigned short* M = X + 4608;
        const float b2a = mb2[c0 + lr];
        const float b2b = mb2[c0 + 16 + lr];
        #pragma unroll
        for (int mt = 0; mt < 2; ++mt)
            #pragma unroll
            for (int nt = 0; nt < 2; ++nt) {
                const int n = c0 + nt * 16 + lr;
                const float bb = nt ? b2b : b2a;
                #pragma unroll
                for (int r = 0; r < 4; ++r) {
                    const int m = mt * 16 + (lane >> 4) * 4 + r;
                    const float v = acc2[mt][nt][r] + bb;
                    M[m * TST + n] = f2bf(v);
                    if (MODE == 0)
                        atomicAdd(&agg_f32[(size_t)rows[m] * HD + n], v);
                }
            }
    }
    __syncthreads();   // B4: M complete — LAST barrier; all atomics issue below

    // ---- MODE2: packed-bf16 pair scatter (8 dword pairs / thread) ----
    if (MODE == 2) {
        const unsigned short* M = X + 4608;
        #pragma unroll
        for (int t = 0; t < 8; ++t) {
            const int idx = t * 256 + tid;     // 0..2047
            const int e   = idx >> 6;          // edge slot (wave-uniform)
            const int pc  = idx & 63;          // channel pair
            const unsigned pk = *reinterpret_cast<const unsigned*>(&M[e * TST + pc * 2]);
            atomic_pk_bf16(agg_bf + ((size_t)rows[e] * HD + pc * 2), pk);
        }
    }

    // ---- coord MLP (barrier-free tail) ----
    if (tid < EPB * 4) {
        const int e = tid >> 2, q = tid & 3;
        const unsigned short* M = X + 4608;
        float sa = 0.f, sb = 0.f, sc = 0.f, sd = 0.f;
        #pragma unroll
        for (int k8 = 0; k8 < 16; ++k8) {
            short8v mm = *reinterpret_cast<const short8v*>(&M[e * TST + k8 * 8]);
            const float* cwp = cw1 + (k8 * 8) * 4 + q;
            sa = fmaf(bf2f((unsigned short)mm[0]), cwp[0],  sa);
            sb = fmaf(bf2f((unsigned short)mm[1]), cwp[4],  sb);
            sc = fmaf(bf2f((unsigned short)mm[2]), cwp[8],  sc);
            sd = fmaf(bf2f((unsigned short)mm[3]), cwp[12], sd);
            sa = fmaf(bf2f((unsigned short)mm[4]), cwp[16], sa);
            sb = fmaf(bf2f((unsigned short)mm[5]), cwp[20], sb);
            sc = fmaf(bf2f((unsigned short)mm[6]), cwp[24], sc);
            sd = fmaf(bf2f((unsigned short)mm[7]), cwp[28], sd);
        }
        const float s  = cb1[q] + ((sa + sb) + (sc + sd));
        const float c1 = silu(s);
        float t = c1 * cw2[q];
        t += __shfl_xor(t, 1, 4);
        t += __shfl_xor(t, 2, 4);
        const float cwt = t + cb2[0];
        if (q < 3)
            atomicAdd(&agg_trans[rows[e] * 3 + q], cd[e][q] * cwt);
    }
}

// ============ node kernel ============
template <int MODE>
__global__ __launch_bounds__(256, 6) void egnn_node_mfma(
    const float* __restrict__ h, const unsigned short* __restrict__ hb,
    const float* __restrict__ pos,
    const unsigned short* __restrict__ n1t, const float* __restrict__ nb1,
    const unsigned short* __restrict__ n2t, const float* __restrict__ nb2,
    const float* __restrict__ agg_f32, const unsigned short* __restrict__ agg_bf,
    float* __restrict__ out_h, float* __restrict__ out_pos)
{
    __shared__ __align__(16) unsigned short Xn[NPB * NXST];  // [h bf16 | agg bf16]
    __shared__ __align__(16) unsigned short Tn[NPB * TST];

    const int tid  = threadIdx.x;
    const int lane = tid & 63;
    const int w    = tid >> 6;
    const int lr   = lane & 15;
    const int lk   = (lane >> 4) * 8;
    const int c0   = w * 32;
    const int n0   = blockIdx.x * NPB;

    // ---- load X: 64 slots (32 h rows, 32 agg rows), 16 thr x 16B each ----
    #pragma unroll
    for (int p = 0; p < 4; ++p) {
        const int slot  = p * 16 + (tid >> 4);
        const int pc    = tid & 15;
        const int s     = slot & 31;
        const int isagg = slot >> 5;
        int n = n0 + s; if (n >= NN) n = NN - 1;
        short8v v;
        if (MODE == 2) {
            const unsigned short* src = isagg ? (agg_bf + (size_t)n * HD)
                                              : (hb + (size_t)n * HD);
            v = *reinterpret_cast<const short8v*>(src + pc * 8);
        } else {
            const float* src = isagg ? (agg_f32 + (size_t)n * HD)
                                     : (h + (size_t)n * HD);
            float4 f0 = *reinterpret_cast<const float4*>(src + pc * 8);
            float4 f1 = *reinterpret_cast<const float4*>(src + pc * 8 + 4);
            v[0] = (short)f2bf(f0.x); v[1] = (short)f2bf(f0.y);
            v[2] = (short)f2bf(f0.z); v[3] = (short)f2bf(f0.w);
            v[4] = (short)f2bf(f1.x); v[5] = (short)f2bf(f1.y);
            v[6] = (short)f2bf(f1.z); v[7] = (short)f2bf(f1.w);
        }
        *reinterpret_cast<short8v*>(&Xn[s * NXST + isagg * 128 + pc * 8]) = v;
    }
    __syncthreads();   // B1

    // ---- layer 1 ----
    f32x4 acc1[2][2] = {};
    {
        const unsigned short* xa0 = &Xn[lr * NXST + lk];
        const unsigned short* xa1 = xa0 + 16 * NXST;
        const unsigned short* wb0 = n1t + (size_t)(c0 + lr) * 256 + lk;
        const unsigned short* wb1 = wb0 + 16 * 256;
        #pragma unroll
        for (int ks = 0; ks < 8; ++ks) {
            const int k0 = ks * 32;
            short8v a0 = *reinterpret_cast<const short8v*>(xa0 + k0);
            short8v a1 = *reinterpret_cast<const short8v*>(xa1 + k0);
            short8v b0 = *reinterpret_cast<const short8v*>(wb0 + k0);
            short8v b1 = *reinterpret_cast<const short8v*>(wb1 + k0);
            acc1[0][0] = MFMA_BF16(a0, b0, acc1[0][0]);
            acc1[0][1] = MFMA_BF16(a0, b1, acc1[0][1]);
            acc1[1][0] = MFMA_BF16(a1, b0, acc1[1][0]);
            acc1[1][1] = MFMA_BF16(a1, b1, acc1[1][1]);
        }
    }
    {
        const float b1a = nb1[c0 + lr];
        const float b1b = nb1[c0 + 16 + lr];
        #pragma unroll
        for (int mt = 0; mt < 2; ++mt)
            #pragma unroll
            for (int nt = 0; nt < 2; ++nt) {
                const int n = c0 + nt * 16 + lr;
                const float bb = nt ? b1b : b1a;
                #pragma unroll
                for (int r = 0; r < 4; ++r) {
                    const int m = mt * 16 + (lane >> 4) * 4 + r;
                    Tn[m * TST + n] = f2bf(silu(acc1[mt][nt][r] + bb));
                }
            }
    }
    __syncthreads();   // B2

    // ---- layer 2 ----
    f32x4 acc2[2][2] = {};
    {
        const unsigned short* ta0 = &Tn[lr * TST + lk];
        const unsigned short* ta1 = ta0 + 16 * TST;
        const unsigned short* wb0 = n2t + (size_t)(c0 + lr) * 128 + lk;
        const unsigned short* wb1 = wb0 + 16 * 128;
        #pragma unroll
        for (int ks = 0; ks < 4; ++ks) {
            const int k0 = ks * 32;
            short8v a0 = *reinterpret_cast<const short8v*>(ta0 + k0);
            short8v a1 = *reinterpret_cast<const short8v*>(ta1 + k0);
            short8v b0 = *reinterpret_cast<const short8v*>(wb0 + k0);
            short8v b1 = *reinterpret_cast<const short8v*>(wb1 + k0);
            acc2[0][0] = MFMA_BF16(a0, b0, acc2[0][0]);
            acc2[0][1] = MFMA_BF16(a0, b1, acc2[0][1]);
            acc2[1][0] = MFMA_BF16(a1, b0, acc2[1][0]);
            acc2[1][1] = MFMA_BF16(a1, b1, acc2[1][1]);
        }
    }
    {   // h_new = h + (acc2 + nb2)
        const float b2a = nb2[c0 + lr];
        const float b2b = nb2[c0 + 16 + lr];
        #pragma unroll
        for (int mt = 0; mt < 2; ++mt)
            #pragma unroll
            for (int nt = 0; nt < 2; ++nt) {
                const int n = c0 + nt * 16 + lr;
                const float bb = nt ? b2b : b2a;
                #pragma unroll
                for (int r = 0; r < 4; ++r) {
                    const int m = mt * 16 + (lane >> 4) * 4 + r;
                    const int node = n0 + m;
                    if (node < NN) {
                        const size_t o = (size_t)node * HD + n;
                        out_h[o] = h[o] + acc2[mt][nt][r] + bb;
                    }
                }
            }
    }
    if (tid < NPB * 3) {
        const int s = tid / 3, a = tid % 3;
        const int node = n0 + s;
        if (node < NN) {
            const size_t idx = (size_t)node * 3 + a;
            out_pos[idx] = pos[idx] + out_pos[idx];
        }
    }
}

extern "C" void kernel_launch(void* const* d_in, const int* in_sizes, int n_in,
                              void* d_out, int out_size, void* d_ws, size_t ws_size,
                              hipStream_t stream) {
    const float* h   = (const float*)d_in[0];
    const float* pos = (const float*)d_in[1];
    const int*   ei  = (const int*)d_in[2];
    const float* mw1 = (const float*)d_in[3];
    const float* mb1 = (const float*)d_in[4];
    const float* mw2 = (const float*)d_in[5];
    const float* mb2 = (const float*)d_in[6];
    const float* cw1 = (const float*)d_in[7];
    const float* cb1 = (const float*)d_in[8];
    const float* cw2 = (const float*)d_in[9];
    const float* cb2 = (const float*)d_in[10];
    const float* nw1 = (const float*)d_in[11];
    const float* nb1 = (const float*)d_in[12];
    const float* nw2 = (const float*)d_in[13];
    const float* nb2 = (const float*)d_in[14];

    float* out     = (float*)d_out;
    float* out_h   = out;                       // agg_msg(f32 fallback) -> h_new
    float* out_pos = out + (size_t)NN * HD;     // agg_trans -> pos_new

    // ws layout (bf16): [wt: WTOT][hb: NN*HD][agg_bf: NN*HD]
    unsigned short* wt  = (unsigned short*)d_ws;
    unsigned short* w1t = wt;
    unsigned short* w2t = wt + W1T_N;
    unsigned short* n1t = wt + W1T_N + W2T_N;
    unsigned short* n2t = wt + W1T_N + W2T_N + N1T_N;
    unsigned short* hb  = wt + WTOT;
    unsigned short* agg_bf = hb + (size_t)NN * HD;
    const size_t need = (size_t)WTOT * 2 + 2 * (size_t)NN * HD * 2;
    const int mode2 = (ws_size >= need) ? 1 : 0;

    prep_weights<<<(WTOT + 255) / 256, 256, 0, stream>>>(mw1, mw2, nw1, nw2, wt);

    if (mode2) {
        prep_h<<<(NN * HD / 4 + 255) / 256, 256, 0, stream>>>(h, hb);
        hipMemsetAsync(agg_bf, 0, (size_t)NN * HD * 2, stream);
        hipMemsetAsync(out_pos, 0, (size_t)NN * 3 * sizeof(float), stream);
        egnn_edge_mfma<2><<<NB_E, 256, 0, stream>>>(
            h, hb, pos, ei, w1t, mb1, w2t, mb2, cw1, cb1, cw2, cb2,
            out_h, agg_bf, out_pos);
        egnn_node_mfma<2><<<NB_N, 256, 0, stream>>>(
            h, hb, pos, n1t, nb1, n2t, nb2, out_h, agg_bf, out_h, out_pos);
    } else {
        hipMemsetAsync(d_out, 0, (size_t)out_size * sizeof(float), stream);
        egnn_edge_mfma<0><<<NB_E, 256, 0, stream>>>(
            h, hb, pos, ei, w1t, mb1, w2t, mb2, cw1, cb1, cw2, cb2,
            out_h, agg_bf, out_pos);
        egnn_node_mfma<0><<<NB_N, 256, 0, stream>>>(
            h, hb, pos, n1t, nb1, n2t, nb2, out_h, agg_bf, out_h, out_pos);
    }
}

// Round 5
// 279.864 us; speedup vs baseline: 5.0727x; 1.0062x over previous
//
#include <hip/hip_runtime.h>

#define HD 128
#define NN 50000
#define NE 600000
#define EPB 64            // edges per block (edge kernel)
#define NPB 32            // nodes per block (node kernel)
#define XST 296           // edge X LDS row stride (bf16)
#define TST 136           // T/M LDS row stride (bf16)
#define K1P 288           // padded K for edge layer1
#define NXST 264          // node X LDS row stride (bf16)
#define NB_E (NE / EPB)   // 9375
#define NB_N ((NN + NPB - 1) / NPB)

typedef __attribute__((ext_vector_type(8))) short short8v;
typedef __attribute__((ext_vector_type(4))) short short4v;
typedef __attribute__((ext_vector_type(4))) float f32x4;

#define MFMA_BF16(a, b, c) __builtin_amdgcn_mfma_f32_16x16x32_bf16(a, b, c, 0, 0, 0)

__device__ __forceinline__ float silu(float x) {
    return x / (1.0f + __expf(-x));
}
__device__ __forceinline__ unsigned short f2bf(float x) {   // RNE f32 -> bf16
    unsigned u = __float_as_uint(x);
    unsigned r = (u + 0x7FFFu + ((u >> 16) & 1u)) >> 16;
    return (unsigned short)r;
}
__device__ __forceinline__ float bf2f(unsigned short u) {
    return __uint_as_float((unsigned)u << 16);
}
__device__ __forceinline__ void atomic_pk_bf16(unsigned short* dst, unsigned pk) {
    asm volatile("global_atomic_pk_add_bf16 %0, %1, off" :: "v"(dst), "v"(pk) : "memory");
}

// ---- prep: transpose+convert weights to bf16 in ws ----
// layout: w1t[128][288] | w2t[128][128] | n1t[128][256] | n2t[128][128] | cw1p[16][128]
#define W1T_N (128 * K1P)
#define W2T_N (128 * 128)
#define N1T_N (128 * 256)
#define N2T_N (128 * 128)
#define C1P_N (16 * 128)
#define WTOT  (W1T_N + W2T_N + N1T_N + N2T_N + C1P_N)  // 104448

__global__ __launch_bounds__(256) void prep_weights(
    const float* __restrict__ mw1, const float* __restrict__ mw2,
    const float* __restrict__ nw1, const float* __restrict__ nw2,
    const float* __restrict__ cw1, unsigned short* __restrict__ wt)
{
    int idx = blockIdx.x * 256 + threadIdx.x;
    if (idx < W1T_N) {
        int c = idx / K1P, k = idx % K1P;
        wt[idx] = (k < 257) ? f2bf(mw1[(size_t)k * HD + c]) : (unsigned short)0;
    } else if (idx < W1T_N + W2T_N) {
        int i = idx - W1T_N;
        int c = i / 128, k = i % 128;
        wt[idx] = f2bf(mw2[(size_t)k * HD + c]);
    } else if (idx < W1T_N + W2T_N + N1T_N) {
        int i = idx - (W1T_N + W2T_N);
        int c = i / 256, k = i % 256;
        wt[idx] = f2bf(nw1[(size_t)k * HD + c]);
    } else if (idx < W1T_N + W2T_N + N1T_N + N2T_N) {
        int i = idx - (W1T_N + W2T_N + N1T_N);
        int c = i / 128, k = i % 128;
        wt[idx] = f2bf(nw2[(size_t)k * HD + c]);
    } else if (idx < WTOT) {
        int i = idx - (W1T_N + W2T_N + N1T_N + N2T_N);
        int n = i / 128, k = i % 128;
        wt[idx] = (n < 4) ? f2bf(cw1[(size_t)k * 4 + n]) : (unsigned short)0;
    }
}

__global__ __launch_bounds__(256) void prep_h(
    const float* __restrict__ h, unsigned short* __restrict__ hb)
{
    size_t idx = (size_t)(blockIdx.x * 256 + threadIdx.x) * 4;
    float4 f = *reinterpret_cast<const float4*>(h + idx);
    short4v v;
    v[0] = (short)f2bf(f.x); v[1] = (short)f2bf(f.y);
    v[2] = (short)f2bf(f.z); v[3] = (short)f2bf(f.w);
    *reinterpret_cast<short4v*>(hb + idx) = v;
}

// ============ edge kernel: 64 edges/block, 4 waves x (64x32 tile) ============
// MODE 0: f32 gather, f32 atomics into agg_f32. MODE 2: bf16 gather, pk-bf16 atomics.
template <int MODE>
__global__ __launch_bounds__(256, 4) void egnn_edge_mfma(
    const float* __restrict__ h, const unsigned short* __restrict__ hb,
    const float* __restrict__ pos, const int* __restrict__ ei,
    const unsigned short* __restrict__ w1t, const float* __restrict__ mb1,
    const unsigned short* __restrict__ w2t, const float* __restrict__ mb2,
    const unsigned short* __restrict__ cw1p, const float* __restrict__ cb1,
    const float* __restrict__ cw2, const float* __restrict__ cb2,
    float* __restrict__ agg_f32, unsigned short* __restrict__ agg_bf,
    float* __restrict__ agg_trans)
{
    // X live ranges: A) gathered [h_r|h_c|radial|pad] (18944 entries);
    //                B) T (silu L1) in [0, 8704);  C) M (msg bf16) in [8704, 17408)
    __shared__ __align__(16) unsigned short X[EPB * XST];
    __shared__ int rows[EPB];
    __shared__ float cd[EPB][3];

    const int tid  = threadIdx.x;
    const int lane = tid & 63;
    const int w    = tid >> 6;
    const int lr   = lane & 15;
    const int lk   = (lane >> 4) * 8;
    const int c0   = w * 32;
    const int e0   = blockIdx.x * EPB;

    // ---- phase 0 ----
    if (tid < EPB) {
        const int r = ei[e0 + tid];
        const int c = ei[(size_t)NE + e0 + tid];
        rows[tid] = r;
        const float d0 = pos[r * 3 + 0] - pos[c * 3 + 0];
        const float d1 = pos[r * 3 + 1] - pos[c * 3 + 1];
        const float d2 = pos[r * 3 + 2] - pos[c * 3 + 2];
        cd[tid][0] = d0; cd[tid][1] = d1; cd[tid][2] = d2;
        X[tid * XST + 256] = f2bf(d0 * d0 + d1 * d1 + d2 * d2 + 1e-8f);
    }
    for (int idx = tid; idx < EPB * 31; idx += 256) {   // zero pad cols 257..287
        const int e = idx / 31, c = 257 + idx % 31;
        X[e * XST + c] = 0;
    }
    #pragma unroll
    for (int p = 0; p < 8; ++p) {       // 128 row-slots x 256B, 16 thr x 16B each
        const int slot  = p * 16 + (tid >> 4);
        const int pc    = tid & 15;
        const int e     = slot & 63;
        const int iscol = slot >> 6;
        const int src   = ei[(size_t)(iscol ? NE : 0) + e0 + e];
        short8v v;
        if (MODE >= 1) {
            v = *reinterpret_cast<const short8v*>(hb + (size_t)src * HD + pc * 8);
        } else {
            const float* hp = h + (size_t)src * HD + pc * 8;
            float4 f0 = *reinterpret_cast<const float4*>(hp);
            float4 f1 = *reinterpret_cast<const float4*>(hp + 4);
            v[0] = (short)f2bf(f0.x); v[1] = (short)f2bf(f0.y);
            v[2] = (short)f2bf(f0.z); v[3] = (short)f2bf(f0.w);
            v[4] = (short)f2bf(f1.x); v[5] = (short)f2bf(f1.y);
            v[6] = (short)f2bf(f1.z); v[7] = (short)f2bf(f1.w);
        }
        *reinterpret_cast<short8v*>(&X[e * XST + iscol * 128 + pc * 8]) = v;
    }
    __syncthreads();   // B1: X complete

    // ---- layer 1: X[64,288] @ W1T^T (64x32 tile per wave) ----
    f32x4 acc1[4][2] = {};
    {
        const unsigned short* xa = &X[lr * XST + lk];
        const unsigned short* wb0 = w1t + (size_t)(c0 + lr) * K1P + lk;
        const unsigned short* wb1 = wb0 + 16 * K1P;
        #pragma unroll
        for (int ks = 0; ks < 9; ++ks) {
            const int k0 = ks * 32;
            short8v b0 = *reinterpret_cast<const short8v*>(wb0 + k0);
            short8v b1 = *reinterpret_cast<const short8v*>(wb1 + k0);
            #pragma unroll
            for (int mt = 0; mt < 4; ++mt) {
                short8v a = *reinterpret_cast<const short8v*>(xa + mt * 16 * XST + k0);
                acc1[mt][0] = MFMA_BF16(a, b0, acc1[mt][0]);
                acc1[mt][1] = MFMA_BF16(a, b1, acc1[mt][1]);
            }
        }
    }
    __syncthreads();   // B2: X reads retired -> safe to alias

    {   // silu -> T (aliased into X[0, 8704))
        unsigned short* T = X;
        const float b1a = mb1[c0 + lr];
        const float b1b = mb1[c0 + 16 + lr];
        #pragma unroll
        for (int mt = 0; mt < 4; ++mt)
            #pragma unroll
            for (int nt = 0; nt < 2; ++nt) {
                const int n = c0 + nt * 16 + lr;
                const float bb = nt ? b1b : b1a;
                #pragma unroll
                for (int r = 0; r < 4; ++r) {
                    const int m = mt * 16 + (lane >> 4) * 4 + r;
                    T[m * TST + n] = f2bf(silu(acc1[mt][nt][r] + bb));
                }
            }
    }
    __syncthreads();   // B3: T complete

    // ---- layer 2: T[64,128] @ W2T^T -> msg ----
    f32x4 acc2[4][2] = {};
    {
        const unsigned short* ta = &X[lr * TST + lk];
        const unsigned short* wb0 = w2t + (size_t)(c0 + lr) * 128 + lk;
        const unsigned short* wb1 = wb0 + 16 * 128;
        #pragma unroll
        for (int ks = 0; ks < 4; ++ks) {
            const int k0 = ks * 32;
            short8v b0 = *reinterpret_cast<const short8v*>(wb0 + k0);
            short8v b1 = *reinterpret_cast<const short8v*>(wb1 + k0);
            #pragma unroll
            for (int mt = 0; mt < 4; ++mt) {
                short8v a = *reinterpret_cast<const short8v*>(ta + mt * 16 * TST + k0);
                acc2[mt][0] = MFMA_BF16(a, b0, acc2[mt][0]);
                acc2[mt][1] = MFMA_BF16(a, b1, acc2[mt][1]);
            }
        }
    }
    {   // msg -> M (bf16, X entries [8704, 17408)); MODE0 also f32 atomics
        unsigned short* M = X + 8704;
        const float b2a = mb2[c0 + lr];
        const float b2b = mb2[c0 + 16 + lr];
        #pragma unroll
        for (int mt = 0; mt < 4; ++mt)
            #pragma unroll
            for (int nt = 0; nt < 2; ++nt) {
                const int n = c0 + nt * 16 + lr;
                const float bb = nt ? b2b : b2a;
                #pragma unroll
                for (int r = 0; r < 4; ++r) {
                    const int m = mt * 16 + (lane >> 4) * 4 + r;
                    const float v = acc2[mt][nt][r] + bb;
                    M[m * TST + n] = f2bf(v);
                    if (MODE == 0)
                        atomicAdd(&agg_f32[(size_t)rows[m] * HD + n], v);
                }
            }
    }
    __syncthreads();   // B4: M complete — LAST barrier

    // ---- MODE2: packed-bf16 pair scatter (16 x 256B wave-uniform rows) ----
    if (MODE == 2) {
        const unsigned short* M = X + 8704;
        #pragma unroll
        for (int t = 0; t < 16; ++t) {
            const int idx = t * 256 + tid;     // 0..4095
            const int e   = idx >> 6;          // edge slot (wave-uniform)
            const int pc  = idx & 63;          // channel pair
            const unsigned pk = *reinterpret_cast<const unsigned*>(&M[e * TST + pc * 2]);
            atomic_pk_bf16(agg_bf + ((size_t)rows[e] * HD + pc * 2), pk);
        }
    }

    // ---- coord MLP via MFMA: per wave, its 16 edges: M[16,128] @ cw1p^T ----
    {
        const unsigned short* M = X + 8704;
        f32x4 accc = {};
        const unsigned short* ma = &M[(w * 16 + lr) * TST + lk];
        const unsigned short* cb = cw1p + (size_t)lr * 128 + lk;
        #pragma unroll
        for (int ks = 0; ks < 4; ++ks) {
            short8v a = *reinterpret_cast<const short8v*>(ma + ks * 32);
            short8v b = *reinterpret_cast<const short8v*>(cb + ks * 32);
            accc = MFMA_BF16(a, b, accc);
        }
        const int q = lr;                       // output col (0..15, valid 0..3)
        const float b1q = (q < 4) ? cb1[q] : 0.f;
        const float c2q = (q < 4) ? cw2[q] : 0.f;
        #pragma unroll
        for (int r = 0; r < 4; ++r) {
            float t = silu(accc[r] + b1q) * c2q;
            t += __shfl_xor(t, 1);
            t += __shfl_xor(t, 2);              // lanes q=0..3 hold sum over q
            const float cwt = t + cb2[0];
            if (q < 3) {
                const int e = w * 16 + (lane >> 4) * 4 + r;
                atomicAdd(&agg_trans[rows[e] * 3 + q], cd[e][q] * cwt);
            }
        }
    }
}

// ============ node kernel ============
template <int MODE>
__global__ __launch_bounds__(256, 6) void egnn_node_mfma(
    const float* __restrict__ h, const unsigned short* __restrict__ hb,
    const float* __restrict__ pos,
    const unsigned short* __restrict__ n1t, const float* __restrict__ nb1,
    const unsigned short* __restrict__ n2t, const float* __restrict__ nb2,
    const float* __restrict__ agg_f32, const unsigned short* __restrict__ agg_bf,
    float* __restrict__ out_h, float* __restrict__ out_pos)
{
    __shared__ __align__(16) unsigned short Xn[NPB * NXST];
    __shared__ __align__(16) unsigned short Tn[NPB * TST];

    const int tid  = threadIdx.x;
    const int lane = tid & 63;
    const int w    = tid >> 6;
    const int lr   = lane & 15;
    const int lk   = (lane >> 4) * 8;
    const int c0   = w * 32;
    const int n0   = blockIdx.x * NPB;

    #pragma unroll
    for (int p = 0; p < 4; ++p) {
        const int slot  = p * 16 + (tid >> 4);
        const int pc    = tid & 15;
        const int s     = slot & 31;
        const int isagg = slot >> 5;
        int n = n0 + s; if (n >= NN) n = NN - 1;
        short8v v;
        if (MODE == 2) {
            const unsigned short* src = isagg ? (agg_bf + (size_t)n * HD)
                                              : (hb + (size_t)n * HD);
            v = *reinterpret_cast<const short8v*>(src + pc * 8);
        } else {
            const float* src = isagg ? (agg_f32 + (size_t)n * HD)
                                     : (h + (size_t)n * HD);
            float4 f0 = *reinterpret_cast<const float4*>(src + pc * 8);
            float4 f1 = *reinterpret_cast<const float4*>(src + pc * 8 + 4);
            v[0] = (short)f2bf(f0.x); v[1] = (short)f2bf(f0.y);
            v[2] = (short)f2bf(f0.z); v[3] = (short)f2bf(f0.w);
            v[4] = (short)f2bf(f1.x); v[5] = (short)f2bf(f1.y);
            v[6] = (short)f2bf(f1.z); v[7] = (short)f2bf(f1.w);
        }
        *reinterpret_cast<short8v*>(&Xn[s * NXST + isagg * 128 + pc * 8]) = v;
    }
    __syncthreads();

    f32x4 acc1[2][2] = {};
    {
        const unsigned short* xa0 = &Xn[lr * NXST + lk];
        const unsigned short* xa1 = xa0 + 16 * NXST;
        const unsigned short* wb0 = n1t + (size_t)(c0 + lr) * 256 + lk;
        const unsigned short* wb1 = wb0 + 16 * 256;
        #pragma unroll
        for (int ks = 0; ks < 8; ++ks) {
            const int k0 = ks * 32;
            short8v a0 = *reinterpret_cast<const short8v*>(xa0 + k0);
            short8v a1 = *reinterpret_cast<const short8v*>(xa1 + k0);
            short8v b0 = *reinterpret_cast<const short8v*>(wb0 + k0);
            short8v b1 = *reinterpret_cast<const short8v*>(wb1 + k0);
            acc1[0][0] = MFMA_BF16(a0, b0, acc1[0][0]);
            acc1[0][1] = MFMA_BF16(a0, b1, acc1[0][1]);
            acc1[1][0] = MFMA_BF16(a1, b0, acc1[1][0]);
            acc1[1][1] = MFMA_BF16(a1, b1, acc1[1][1]);
        }
    }
    {
        const float b1a = nb1[c0 + lr];
        const float b1b = nb1[c0 + 16 + lr];
        #pragma unroll
        for (int mt = 0; mt < 2; ++mt)
            #pragma unroll
            for (int nt = 0; nt < 2; ++nt) {
                const int n = c0 + nt * 16 + lr;
                const float bb = nt ? b1b : b1a;
                #pragma unroll
                for (int r = 0; r < 4; ++r) {
                    const int m = mt * 16 + (lane >> 4) * 4 + r;
                    Tn[m * TST + n] = f2bf(silu(acc1[mt][nt][r] + bb));
                }
            }
    }
    __syncthreads();

    f32x4 acc2[2][2] = {};
    {
        const unsigned short* ta0 = &Tn[lr * TST + lk];
        const unsigned short* ta1 = ta0 + 16 * TST;
        const unsigned short* wb0 = n2t + (size_t)(c0 + lr) * 128 + lk;
        const unsigned short* wb1 = wb0 + 16 * 128;
        #pragma unroll
        for (int ks = 0; ks < 4; ++ks) {
            const int k0 = ks * 32;
            short8v a0 = *reinterpret_cast<const short8v*>(ta0 + k0);
            short8v a1 = *reinterpret_cast<const short8v*>(ta1 + k0);
            short8v b0 = *reinterpret_cast<const short8v*>(wb0 + k0);
            short8v b1 = *reinterpret_cast<const short8v*>(wb1 + k0);
            acc2[0][0] = MFMA_BF16(a0, b0, acc2[0][0]);
            acc2[0][1] = MFMA_BF16(a0, b1, acc2[0][1]);
            acc2[1][0] = MFMA_BF16(a1, b0, acc2[1][0]);
            acc2[1][1] = MFMA_BF16(a1, b1, acc2[1][1]);
        }
    }
    {
        const float b2a = nb2[c0 + lr];
        const float b2b = nb2[c0 + 16 + lr];
        #pragma unroll
        for (int mt = 0; mt < 2; ++mt)
            #pragma unroll
            for (int nt = 0; nt < 2; ++nt) {
                const int n = c0 + nt * 16 + lr;
                const float bb = nt ? b2b : b2a;
                #pragma unroll
                for (int r = 0; r < 4; ++r) {
                    const int m = mt * 16 + (lane >> 4) * 4 + r;
                    const int node = n0 + m;
                    if (node < NN) {
                        const size_t o = (size_t)node * HD + n;
                        out_h[o] = h[o] + acc2[mt][nt][r] + bb;
                    }
                }
            }
    }
    if (tid < NPB * 3) {
        const int s = tid / 3, a = tid % 3;
        const int node = n0 + s;
        if (node < NN) {
            const size_t idx = (size_t)node * 3 + a;
            out_pos[idx] = pos[idx] + out_pos[idx];
        }
    }
}

extern "C" void kernel_launch(void* const* d_in, const int* in_sizes, int n_in,
                              void* d_out, int out_size, void* d_ws, size_t ws_size,
                              hipStream_t stream) {
    const float* h   = (const float*)d_in[0];
    const float* pos = (const float*)d_in[1];
    const int*   ei  = (const int*)d_in[2];
    const float* mw1 = (const float*)d_in[3];
    const float* mb1 = (const float*)d_in[4];
    const float* mw2 = (const float*)d_in[5];
    const float* mb2 = (const float*)d_in[6];
    const float* cw1 = (const float*)d_in[7];
    const float* cb1 = (const float*)d_in[8];
    const float* cw2 = (const float*)d_in[9];
    const float* cb2 = (const float*)d_in[10];
    const float* nw1 = (const float*)d_in[11];
    const float* nb1 = (const float*)d_in[12];
    const float* nw2 = (const float*)d_in[13];
    const float* nb2 = (const float*)d_in[14];

    float* out     = (float*)d_out;
    float* out_h   = out;
    float* out_pos = out + (size_t)NN * HD;

    // ws layout (bf16): [wt: WTOT][hb: NN*HD][agg_bf: NN*HD]
    unsigned short* wt   = (unsigned short*)d_ws;
    unsigned short* w1t  = wt;
    unsigned short* w2t  = wt + W1T_N;
    unsigned short* n1t  = wt + W1T_N + W2T_N;
    unsigned short* n2t  = wt + W1T_N + W2T_N + N1T_N;
    unsigned short* cw1p = wt + W1T_N + W2T_N + N1T_N + N2T_N;
    unsigned short* hb   = wt + WTOT;
    unsigned short* agg_bf = hb + (size_t)NN * HD;
    const size_t need = (size_t)WTOT * 2 + 2 * (size_t)NN * HD * 2;
    const int mode2 = (ws_size >= need) ? 1 : 0;

    prep_weights<<<(WTOT + 255) / 256, 256, 0, stream>>>(mw1, mw2, nw1, nw2, cw1, wt);

    if (mode2) {
        prep_h<<<(NN * HD / 4 + 255) / 256, 256, 0, stream>>>(h, hb);
        hipMemsetAsync(agg_bf, 0, (size_t)NN * HD * 2, stream);
        hipMemsetAsync(out_pos, 0, (size_t)NN * 3 * sizeof(float), stream);
        egnn_edge_mfma<2><<<NB_E, 256, 0, stream>>>(
            h, hb, pos, ei, w1t, mb1, w2t, mb2, cw1p, cb1, cw2, cb2,
            out_h, agg_bf, out_pos);
        egnn_node_mfma<2><<<NB_N, 256, 0, stream>>>(
            h, hb, pos, n1t, nb1, n2t, nb2, out_h, agg_bf, out_h, out_pos);
    } else {
        hipMemsetAsync(d_out, 0, (size_t)out_size * sizeof(float), stream);
        egnn_edge_mfma<0><<<NB_E, 256, 0, stream>>>(
            h, hb, pos, ei, w1t, mb1, w2t, mb2, cw1p, cb1, cw2, cb2,
            out_h, agg_bf, out_pos);
        egnn_node_mfma<0><<<NB_N, 256, 0, stream>>>(
            h, hb, pos, n1t, nb1, n2t, nb2, out_h, agg_bf, out_h, out_pos);
    }
}